// Round 1
// 419.238 us; speedup vs baseline: 1.1386x; 1.1386x over previous
//
#include <hip/hip_runtime.h>
#include <stdint.h>

#define NEGV -10000000.0f

typedef __attribute__((ext_vector_type(8))) short short8;
typedef __attribute__((ext_vector_type(4))) float f32x4;

__device__ __forceinline__ ushort f2b(float f) {
    uint32_t x = __float_as_uint(f);
    uint32_t r = x + 0x7FFFu + ((x >> 16) & 1u);
    return (ushort)(r >> 16);
}

// ---------------- Kernel 0: per-n prep (once, not once-per-t-tile) ----------------
// Bhat[n][j][d<224] = bf16(U*w_hu + w_h) (zero-padded), c[n][j] = dot(U[j],w_u)+b,
// UT[n][d<224][j]   = bf16(U^T) in k3 B-fragment layout.
__launch_bounds__(256)
__global__ void k0_prep(const float* __restrict__ Ug, const float* __restrict__ wg,
                        const float* __restrict__ bg,
                        ushort* __restrict__ BhatW, ushort* __restrict__ UTW,
                        float* __restrict__ cW) {
    __shared__ __align__(16) float sU[64][200];
    __shared__ float sW[600];
    const int tid = threadIdx.x, lane = tid & 63, wid = tid >> 6;
    const int n = blockIdx.x;

    for (int i = tid; i < 600; i += 256) sW[i] = wg[i];
    for (int r = wid; r < 64; r += 4) {
        const float* urow = Ug + (size_t)(n * 64 + r) * 200;
        if (lane < 50) *(float4*)&sU[r][lane * 4] = *(const float4*)(urow + lane * 4);
    }
    __syncthreads();
    const float bval = bg[0];

    // U^T bf16, rows d (padded to 224), cols j: coalesced 128B stores per iter
    ushort* utn = UTW + (size_t)n * 224 * 64;
    for (int d = wid; d < 224; d += 4)
        utn[d * 64 + lane] = (d < 200) ? f2b(sU[lane][d]) : (ushort)0;

    // Bhat bf16 (padded) + c[j]
    ushort* bhn = BhatW + (size_t)n * 64 * 224;
    for (int r = wid; r < 64; r += 4) {
        float part = 0.f;
        for (int d = lane; d < 224; d += 64) {
            float bh = 0.f;
            if (d < 200) {
                float u = sU[r][d];
                bh = u * sW[400 + d] + sW[d];
                part += u * sW[200 + d];
            }
            bhn[r * 224 + d] = f2b(bh);
        }
        #pragma unroll
        for (int off = 32; off >= 1; off >>= 1) part += __shfl_xor(part, off);
        if (lane == 0) cW[n * 64 + r] = part + bval;
    }
}

// ---------------- Kernel 1: S = H@Bhat^T + c, J-softmax -> P(bf16), S_max ---------
// Direct-to-fragment loads: no H/B LDS staging, only 9.2KB P-staging LDS.
__launch_bounds__(256, 3)
__global__ void k1_gemm1_softmax(const float* __restrict__ Hg,
                                 const ushort* __restrict__ BhatW,
                                 const float* __restrict__ cW,
                                 const float* __restrict__ qmg,
                                 ushort* __restrict__ Pws,
                                 float* __restrict__ SmaxWs) {
    __shared__ ushort sP[64][72];
    const int tid = threadIdx.x, lane = tid & 63, wid = tid >> 6;
    const int g = lane >> 4, li = lane & 15;
    const int n = blockIdx.y, t0 = blockIdx.x * 64;

    const float*  Hrow = Hg + (size_t)(n * 1024 + t0 + 16 * wid + li) * 200;
    const ushort* Bn   = BhatW + (size_t)n * 64 * 224;

    f32x4 acc[4];
    #pragma unroll
    for (int jt = 0; jt < 4; ++jt) acc[jt] = (f32x4){0.f, 0.f, 0.f, 0.f};

    #pragma unroll
    for (int kc = 0; kc < 7; ++kc) {
        short8 av;
        if (kc < 6 || g == 0) {   // kc==6,g>0 would read past d=200 (and off H's end)
            float4 h0 = *(const float4*)(Hrow + kc * 32 + g * 8);
            float4 h1 = *(const float4*)(Hrow + kc * 32 + g * 8 + 4);
            av[0] = (short)f2b(h0.x); av[1] = (short)f2b(h0.y);
            av[2] = (short)f2b(h0.z); av[3] = (short)f2b(h0.w);
            av[4] = (short)f2b(h1.x); av[5] = (short)f2b(h1.y);
            av[6] = (short)f2b(h1.z); av[7] = (short)f2b(h1.w);
        } else {
            av = (short8){0, 0, 0, 0, 0, 0, 0, 0};
        }
        #pragma unroll
        for (int jt = 0; jt < 4; ++jt) {
            short8 bv = *(const short8*)(Bn + (size_t)(jt * 16 + li) * 224 + kc * 32 + g * 8);
            acc[jt] = __builtin_amdgcn_mfma_f32_16x16x32_bf16(av, bv, acc[jt], 0, 0, 0);
        }
    }

    float cj[4], qm[4];
    #pragma unroll
    for (int jt = 0; jt < 4; ++jt) {
        cj[jt] = cW[n * 64 + jt * 16 + li];
        qm[jt] = qmg[n * 64 + jt * 16 + li];
    }

    #pragma unroll
    for (int reg = 0; reg < 4; ++reg) {
        float x[4], y[4];
        float xm = -1e30f, ym = -1e30f;
        #pragma unroll
        for (int jt = 0; jt < 4; ++jt) {
            float s = acc[jt][reg] + cj[jt];
            x[jt] = s * qm[jt];
            y[jt] = (qm[jt] != 0.f) ? s : NEGV;
            xm = fmaxf(xm, x[jt]); ym = fmaxf(ym, y[jt]);
        }
        #pragma unroll
        for (int off = 1; off <= 8; off <<= 1) {
            xm = fmaxf(xm, __shfl_xor(xm, off));
            ym = fmaxf(ym, __shfl_xor(ym, off));
        }
        float e[4], z = 0.f, zm = 0.f;
        #pragma unroll
        for (int jt = 0; jt < 4; ++jt) {
            e[jt] = __expf(x[jt] - xm);
            z += e[jt]; zm += e[jt] * qm[jt];
        }
        #pragma unroll
        for (int off = 1; off <= 8; off <<= 1) {
            z  += __shfl_xor(z, off);
            zm += __shfl_xor(zm, off);
        }
        float inv = 1.f / (zm + 1e-13f * z);
        int trow = 16 * wid + g * 4 + reg;
        #pragma unroll
        for (int jt = 0; jt < 4; ++jt) sP[trow][jt * 16 + li] = f2b(e[jt] * qm[jt] * inv);
        if (li == 0) SmaxWs[n * 1024 + t0 + trow] = ym;
    }
    __syncthreads();

    uint* pout = (uint*)Pws;
    for (int idx = tid; idx < 2048; idx += 256) {
        int r = idx >> 5, c2 = idx & 31;
        uint v = *(const uint*)&sP[r][c2 * 2];
        pout[(size_t)(n * 1024 + t0 + r) * 32 + c2] = v;
    }
}

// ---------------- Kernel 2a: T-softmax stats -> a coefficients; zero Hbar ---------
__launch_bounds__(256)
__global__ void k2a_softmaxT(const float* __restrict__ cmg,
                             const float* __restrict__ SmaxWs,
                             float* __restrict__ aWs,
                             float* __restrict__ HbarWs) {
    __shared__ float red[8];
    const int tid = threadIdx.x, lane = tid & 63, wid = tid >> 6;
    const int n = blockIdx.x;

    float x[4], m[4];
    #pragma unroll
    for (int i = 0; i < 4; ++i) {
        int t = tid + 256 * i;
        float v = SmaxWs[n * 1024 + t];
        m[i] = cmg[(size_t)n * 1024 + t];
        x[i] = v * m[i];
    }
    float mx = fmaxf(fmaxf(x[0], x[1]), fmaxf(x[2], x[3]));
    #pragma unroll
    for (int off = 32; off >= 1; off >>= 1) mx = fmaxf(mx, __shfl_xor(mx, off));
    if (lane == 0) red[wid] = mx;
    __syncthreads();
    float M = fmaxf(fmaxf(red[0], red[1]), fmaxf(red[2], red[3]));
    __syncthreads();
    float e[4], z = 0.f, zm = 0.f;
    #pragma unroll
    for (int i = 0; i < 4; ++i) {
        e[i] = __expf(x[i] - M);
        z += e[i]; zm += e[i] * m[i];
    }
    #pragma unroll
    for (int off = 32; off >= 1; off >>= 1) {
        z  += __shfl_xor(z, off);
        zm += __shfl_xor(zm, off);
    }
    if (lane == 0) { red[wid] = z; red[4 + wid] = zm; }
    __syncthreads();
    float Z  = red[0] + red[1] + red[2] + red[3];
    float Zm = red[4] + red[5] + red[6] + red[7];
    float inv = 1.f / (Zm + 1e-13f * Z);
    #pragma unroll
    for (int i = 0; i < 4; ++i) aWs[n * 1024 + tid + 256 * i] = e[i] * m[i] * inv;
    if (tid < 200) HbarWs[n * 200 + tid] = 0.f;
}

// ---------------- Kernel 2b: Hbar += a-chunk @ H-chunk (1024-way parallel) -------
__launch_bounds__(256)
__global__ void k2b_hbar(const float* __restrict__ Hg,
                         const float* __restrict__ aWs,
                         float* __restrict__ HbarWs) {
    __shared__ float sA[64];
    const int tid = threadIdx.x;
    const int n = blockIdx.y, t0 = blockIdx.x * 64;
    if (tid < 64) sA[tid] = aWs[n * 1024 + t0 + tid];
    __syncthreads();
    if (tid < 200) {
        const float* hp = Hg + (size_t)(n * 1024 + t0) * 200 + tid;
        float acc = 0.f;
        #pragma unroll 8
        for (int t = 0; t < 64; ++t) acc += sA[t] * hp[(size_t)t * 200];
        atomicAdd(HbarWs + n * 200 + tid, acc);
    }
}

// ---------------- Kernel 3: U_ = P @ U and all G writes, zero LDS -----------------
__launch_bounds__(256, 3)
__global__ void k3_gemm2_out(const float* __restrict__ Hg,
                             const ushort* __restrict__ UTW,
                             const ushort* __restrict__ Pws,
                             const float* __restrict__ HbarWs,
                             float* __restrict__ Gout) {
    const int tid = threadIdx.x, lane = tid & 63, wid = tid >> 6;
    const int g = lane >> 4, li = lane & 15;
    const int n = blockIdx.y, t0 = blockIdx.x * 64;

    const ushort* Prow = Pws + (size_t)(n * 1024 + t0 + 16 * wid + li) * 64;
    const ushort* UTn  = UTW + (size_t)n * 224 * 64;

    f32x4 acc[13];
    #pragma unroll
    for (int dt = 0; dt < 13; ++dt) acc[dt] = (f32x4){0.f, 0.f, 0.f, 0.f};

    #pragma unroll
    for (int kc = 0; kc < 2; ++kc) {
        short8 av = *(const short8*)(Prow + kc * 32 + g * 8);
        #pragma unroll
        for (int dt = 0; dt < 13; ++dt) {
            short8 bv = *(const short8*)(UTn + (size_t)(dt * 16 + li) * 64 + kc * 32 + g * 8);
            acc[dt] = __builtin_amdgcn_mfma_f32_16x16x32_bf16(av, bv, acc[dt], 0, 0, 0);
        }
    }

    // G = [H | U_ | H*U_ | H*Hbar], written in C-layout: 64B line per 16-lane group
    const size_t rowbase = (size_t)(n * 1024 + t0 + 16 * wid + g * 4);
    #pragma unroll
    for (int dt = 0; dt < 13; ++dt) {
        int d = dt * 16 + li;
        if (d < 200) {
            float hb = HbarWs[n * 200 + d];
            #pragma unroll
            for (int reg = 0; reg < 4; ++reg) {
                size_t r = rowbase + reg;
                float h = Hg[r * 200 + d];
                float u = acc[dt][reg];
                float* orow = Gout + r * 800;
                __builtin_nontemporal_store(h,      orow + d);
                __builtin_nontemporal_store(u,      orow + 200 + d);
                __builtin_nontemporal_store(h * u,  orow + 400 + d);
                __builtin_nontemporal_store(h * hb, orow + 600 + d);
            }
        }
    }
}

extern "C" void kernel_launch(void* const* d_in, const int* in_sizes, int n_in,
                              void* d_out, int out_size, void* d_ws, size_t ws_size,
                              hipStream_t stream) {
    (void)in_sizes; (void)n_in; (void)out_size; (void)ws_size;
    const float* Hg  = (const float*)d_in[0];
    const float* Ug  = (const float*)d_in[1];
    const float* cmg = (const float*)d_in[2];
    const float* qmg = (const float*)d_in[3];
    const float* wg  = (const float*)d_in[4];
    const float* bg  = (const float*)d_in[5];
    float* Gout = (float*)d_out;

    char* ws = (char*)d_ws;
    ushort* Pws    = (ushort*)(ws);                    // 64*1024*64*2   = 8,388,608
    float*  SmaxWs = (float*) (ws + 8388608);          // 64*1024*4     =   262,144
    float*  aWs    = (float*) (ws + 8650752);          // 64*1024*4     =   262,144
    float*  HbarWs = (float*) (ws + 8912896);          // 64*200*4      =    51,200
    float*  cWs    = (float*) (ws + 8964096);          // 64*64*4       =    16,384
    ushort* BhatWs = (ushort*)(ws + 8980480);          // 64*64*224*2   = 1,835,008
    ushort* UTWs   = (ushort*)(ws + 10815488);         // 64*224*64*2   = 1,835,008
                                                       // total         = 12,650,496

    dim3 blk(256, 1, 1);
    k0_prep<<<dim3(64, 1, 1), blk, 0, stream>>>(Ug, wg, bg, BhatWs, UTWs, cWs);
    k1_gemm1_softmax<<<dim3(16, 64, 1), blk, 0, stream>>>(Hg, BhatWs, cWs, qmg, Pws, SmaxWs);
    k2a_softmaxT<<<dim3(64, 1, 1), blk, 0, stream>>>(cmg, SmaxWs, aWs, HbarWs);
    k2b_hbar<<<dim3(16, 64, 1), blk, 0, stream>>>(Hg, aWs, HbarWs);
    k3_gemm2_out<<<dim3(16, 64, 1), blk, 0, stream>>>(Hg, UTWs, Pws, HbarWs, Gout);
}

// Round 3
// 324.583 us; speedup vs baseline: 1.4707x; 1.2916x over previous
//
#include <hip/hip_runtime.h>
#include <stdint.h>

#define NEGV -10000000.0f

typedef __attribute__((ext_vector_type(8))) short short8;
typedef __attribute__((ext_vector_type(4))) float f32x4;

__device__ __forceinline__ ushort f2b(float f) {
    uint32_t x = __float_as_uint(f);
    uint32_t r = x + 0x7FFFu + ((x >> 16) & 1u);
    return (ushort)(r >> 16);
}

// ---------------- Kernel 0: per-n prep (once, not once-per-t-tile) ----------------
// Bhat[n][j][d<224] = bf16(U*w_hu + w_h) (zero-padded), c[n][j] = dot(U[j],w_u)+b,
// UT[n][d<224][j]   = bf16(U^T) in k3 B-fragment layout.
__launch_bounds__(256)
__global__ void k0_prep(const float* __restrict__ Ug, const float* __restrict__ wg,
                        const float* __restrict__ bg,
                        ushort* __restrict__ BhatW, ushort* __restrict__ UTW,
                        float* __restrict__ cW) {
    __shared__ __align__(16) float sU[64][200];
    __shared__ float sW[600];
    const int tid = threadIdx.x, lane = tid & 63, wid = tid >> 6;
    const int n = blockIdx.x;

    for (int i = tid; i < 600; i += 256) sW[i] = wg[i];
    for (int r = wid; r < 64; r += 4) {
        const float* urow = Ug + (size_t)(n * 64 + r) * 200;
        if (lane < 50) *(float4*)&sU[r][lane * 4] = *(const float4*)(urow + lane * 4);
    }
    __syncthreads();
    const float bval = bg[0];

    // U^T bf16, rows d (padded to 224), cols j: coalesced 128B stores per iter
    ushort* utn = UTW + (size_t)n * 224 * 64;
    for (int d = wid; d < 224; d += 4)
        utn[d * 64 + lane] = (d < 200) ? f2b(sU[lane][d]) : (ushort)0;

    // Bhat bf16 (padded) + c[j]
    ushort* bhn = BhatW + (size_t)n * 64 * 224;
    for (int r = wid; r < 64; r += 4) {
        float part = 0.f;
        for (int d = lane; d < 224; d += 64) {
            float bh = 0.f;
            if (d < 200) {
                float u = sU[r][d];
                bh = u * sW[400 + d] + sW[d];
                part += u * sW[200 + d];
            }
            bhn[r * 224 + d] = f2b(bh);
        }
        #pragma unroll
        for (int off = 32; off >= 1; off >>= 1) part += __shfl_xor(part, off);
        if (lane == 0) cW[n * 64 + r] = part + bval;
    }
}

// ---------------- Kernel 1: S = H@Bhat^T + c, J-softmax -> P(bf16), S_max ---------
// Direct-to-fragment loads: no H/B LDS staging, only 9.2KB P-staging LDS.
__launch_bounds__(256, 3)
__global__ void k1_gemm1_softmax(const float* __restrict__ Hg,
                                 const ushort* __restrict__ BhatW,
                                 const float* __restrict__ cW,
                                 const float* __restrict__ qmg,
                                 ushort* __restrict__ Pws,
                                 float* __restrict__ SmaxWs) {
    __shared__ ushort sP[64][72];
    const int tid = threadIdx.x, lane = tid & 63, wid = tid >> 6;
    const int g = lane >> 4, li = lane & 15;
    const int n = blockIdx.y, t0 = blockIdx.x * 64;

    const float*  Hrow = Hg + (size_t)(n * 1024 + t0 + 16 * wid + li) * 200;
    const ushort* Bn   = BhatW + (size_t)n * 64 * 224;

    f32x4 acc[4];
    #pragma unroll
    for (int jt = 0; jt < 4; ++jt) acc[jt] = (f32x4){0.f, 0.f, 0.f, 0.f};

    #pragma unroll
    for (int kc = 0; kc < 7; ++kc) {
        short8 av;
        if (kc < 6 || g == 0) {   // kc==6,g>0 would read past d=200 (and off H's end)
            float4 h0 = *(const float4*)(Hrow + kc * 32 + g * 8);
            float4 h1 = *(const float4*)(Hrow + kc * 32 + g * 8 + 4);
            av[0] = (short)f2b(h0.x); av[1] = (short)f2b(h0.y);
            av[2] = (short)f2b(h0.z); av[3] = (short)f2b(h0.w);
            av[4] = (short)f2b(h1.x); av[5] = (short)f2b(h1.y);
            av[6] = (short)f2b(h1.z); av[7] = (short)f2b(h1.w);
        } else {
            av = (short8){0, 0, 0, 0, 0, 0, 0, 0};
        }
        #pragma unroll
        for (int jt = 0; jt < 4; ++jt) {
            short8 bv = *(const short8*)(Bn + (size_t)(jt * 16 + li) * 224 + kc * 32 + g * 8);
            acc[jt] = __builtin_amdgcn_mfma_f32_16x16x32_bf16(av, bv, acc[jt], 0, 0, 0);
        }
    }

    float cj[4], qm[4];
    #pragma unroll
    for (int jt = 0; jt < 4; ++jt) {
        cj[jt] = cW[n * 64 + jt * 16 + li];
        qm[jt] = qmg[n * 64 + jt * 16 + li];
    }

    #pragma unroll
    for (int reg = 0; reg < 4; ++reg) {
        float x[4], y[4];
        float xm = -1e30f, ym = -1e30f;
        #pragma unroll
        for (int jt = 0; jt < 4; ++jt) {
            float s = acc[jt][reg] + cj[jt];
            x[jt] = s * qm[jt];
            y[jt] = (qm[jt] != 0.f) ? s : NEGV;
            xm = fmaxf(xm, x[jt]); ym = fmaxf(ym, y[jt]);
        }
        #pragma unroll
        for (int off = 1; off <= 8; off <<= 1) {
            xm = fmaxf(xm, __shfl_xor(xm, off));
            ym = fmaxf(ym, __shfl_xor(ym, off));
        }
        float e[4], z = 0.f, zm = 0.f;
        #pragma unroll
        for (int jt = 0; jt < 4; ++jt) {
            e[jt] = __expf(x[jt] - xm);
            z += e[jt]; zm += e[jt] * qm[jt];
        }
        #pragma unroll
        for (int off = 1; off <= 8; off <<= 1) {
            z  += __shfl_xor(z, off);
            zm += __shfl_xor(zm, off);
        }
        float inv = 1.f / (zm + 1e-13f * z);
        int trow = 16 * wid + g * 4 + reg;
        #pragma unroll
        for (int jt = 0; jt < 4; ++jt) sP[trow][jt * 16 + li] = f2b(e[jt] * qm[jt] * inv);
        if (li == 0) SmaxWs[n * 1024 + t0 + trow] = ym;
    }
    __syncthreads();

    uint* pout = (uint*)Pws;
    for (int idx = tid; idx < 2048; idx += 256) {
        int r = idx >> 5, c2 = idx & 31;
        uint v = *(const uint*)&sP[r][c2 * 2];
        pout[(size_t)(n * 1024 + t0 + r) * 32 + c2] = v;
    }
}

// ---------------- Kernel 2a: T-softmax stats -> a coefficients; zero Hbar ---------
__launch_bounds__(256)
__global__ void k2a_softmaxT(const float* __restrict__ cmg,
                             const float* __restrict__ SmaxWs,
                             float* __restrict__ aWs,
                             float* __restrict__ HbarWs) {
    __shared__ float red[8];
    const int tid = threadIdx.x, lane = tid & 63, wid = tid >> 6;
    const int n = blockIdx.x;

    float x[4], m[4];
    #pragma unroll
    for (int i = 0; i < 4; ++i) {
        int t = tid + 256 * i;
        float v = SmaxWs[n * 1024 + t];
        m[i] = cmg[(size_t)n * 1024 + t];
        x[i] = v * m[i];
    }
    float mx = fmaxf(fmaxf(x[0], x[1]), fmaxf(x[2], x[3]));
    #pragma unroll
    for (int off = 32; off >= 1; off >>= 1) mx = fmaxf(mx, __shfl_xor(mx, off));
    if (lane == 0) red[wid] = mx;
    __syncthreads();
    float M = fmaxf(fmaxf(red[0], red[1]), fmaxf(red[2], red[3]));
    __syncthreads();
    float e[4], z = 0.f, zm = 0.f;
    #pragma unroll
    for (int i = 0; i < 4; ++i) {
        e[i] = __expf(x[i] - M);
        z += e[i]; zm += e[i] * m[i];
    }
    #pragma unroll
    for (int off = 32; off >= 1; off >>= 1) {
        z  += __shfl_xor(z, off);
        zm += __shfl_xor(zm, off);
    }
    if (lane == 0) { red[wid] = z; red[4 + wid] = zm; }
    __syncthreads();
    float Z  = red[0] + red[1] + red[2] + red[3];
    float Zm = red[4] + red[5] + red[6] + red[7];
    float inv = 1.f / (Zm + 1e-13f * Z);
    #pragma unroll
    for (int i = 0; i < 4; ++i) aWs[n * 1024 + tid + 256 * i] = e[i] * m[i] * inv;
    if (tid < 200) HbarWs[n * 200 + tid] = 0.f;
}

// ---------------- Kernel 2b: Hbar += a-chunk @ H-chunk (1024-way parallel) -------
__launch_bounds__(256)
__global__ void k2b_hbar(const float* __restrict__ Hg,
                         const float* __restrict__ aWs,
                         float* __restrict__ HbarWs) {
    __shared__ float sA[64];
    const int tid = threadIdx.x;
    const int n = blockIdx.y, t0 = blockIdx.x * 64;
    if (tid < 64) sA[tid] = aWs[n * 1024 + t0 + tid];
    __syncthreads();
    if (tid < 200) {
        const float* hp = Hg + (size_t)(n * 1024 + t0) * 200 + tid;
        float acc = 0.f;
        #pragma unroll 8
        for (int t = 0; t < 64; ++t) acc += sA[t] * hp[(size_t)t * 200];
        atomicAdd(HbarWs + n * 200 + tid, acc);
    }
}

// ---------------- Kernel 3: U_ = P @ U; stage U_ in LDS; coalesced float4 G writes
__launch_bounds__(256, 3)
__global__ void k3_gemm2_out(const float* __restrict__ Hg,
                             const ushort* __restrict__ UTW,
                             const ushort* __restrict__ Pws,
                             const float* __restrict__ HbarWs,
                             float* __restrict__ Gout) {
    // row stride 204 floats: 816B = 16B-aligned rows; staging write is 2-way
    // bank conflict (free); total LDS ~53KB -> 3 blocks/CU
    __shared__ __align__(16) float sU2[64][204];
    __shared__ __align__(16) float sHb[200];
    const int tid = threadIdx.x, lane = tid & 63, wid = tid >> 6;
    const int g = lane >> 4, li = lane & 15;
    const int n = blockIdx.y, t0 = blockIdx.x * 64;

    if (tid < 200) sHb[tid] = HbarWs[n * 200 + tid];

    const ushort* Prow = Pws + (size_t)(n * 1024 + t0 + 16 * wid + li) * 64;
    const ushort* UTn  = UTW + (size_t)n * 224 * 64;

    f32x4 acc[13];
    #pragma unroll
    for (int dt = 0; dt < 13; ++dt) acc[dt] = (f32x4){0.f, 0.f, 0.f, 0.f};

    #pragma unroll
    for (int kc = 0; kc < 2; ++kc) {
        short8 av = *(const short8*)(Prow + kc * 32 + g * 8);
        #pragma unroll
        for (int dt = 0; dt < 13; ++dt) {
            short8 bv = *(const short8*)(UTn + (size_t)(dt * 16 + li) * 64 + kc * 32 + g * 8);
            acc[dt] = __builtin_amdgcn_mfma_f32_16x16x32_bf16(av, bv, acc[dt], 0, 0, 0);
        }
    }

    // stage U_ (exact f32) into LDS in C-layout
    #pragma unroll
    for (int dt = 0; dt < 13; ++dt) {
        int d = dt * 16 + li;
        if (d < 200) {
            #pragma unroll
            for (int reg = 0; reg < 4; ++reg)
                sU2[16 * wid + g * 4 + reg][d] = acc[dt][reg];
        }
    }
    __syncthreads();

    // coalesced output: per row, 50 lanes x float4 = 800B contiguous per segment
    for (int r = wid; r < 64; r += 4) {
        const float* hrow = Hg + (size_t)(n * 1024 + t0 + r) * 200;
        float* orow = Gout + (size_t)(n * 1024 + t0 + r) * 800;
        if (lane < 50) {
            int d0 = lane * 4;
            f32x4 h  = *(const f32x4*)(hrow + d0);
            f32x4 u  = *(const f32x4*)&sU2[r][d0];
            f32x4 hb = *(const f32x4*)&sHb[d0];
            f32x4 hu = h * u;
            f32x4 hh = h * hb;
            __builtin_nontemporal_store(h,  (f32x4*)(orow + d0));
            __builtin_nontemporal_store(u,  (f32x4*)(orow + 200 + d0));
            __builtin_nontemporal_store(hu, (f32x4*)(orow + 400 + d0));
            __builtin_nontemporal_store(hh, (f32x4*)(orow + 600 + d0));
        }
    }
}

extern "C" void kernel_launch(void* const* d_in, const int* in_sizes, int n_in,
                              void* d_out, int out_size, void* d_ws, size_t ws_size,
                              hipStream_t stream) {
    (void)in_sizes; (void)n_in; (void)out_size; (void)ws_size;
    const float* Hg  = (const float*)d_in[0];
    const float* Ug  = (const float*)d_in[1];
    const float* cmg = (const float*)d_in[2];
    const float* qmg = (const float*)d_in[3];
    const float* wg  = (const float*)d_in[4];
    const float* bg  = (const float*)d_in[5];
    float* Gout = (float*)d_out;

    char* ws = (char*)d_ws;
    ushort* Pws    = (ushort*)(ws);                    // 64*1024*64*2   = 8,388,608
    float*  SmaxWs = (float*) (ws + 8388608);          // 64*1024*4     =   262,144
    float*  aWs    = (float*) (ws + 8650752);          // 64*1024*4     =   262,144
    float*  HbarWs = (float*) (ws + 8912896);          // 64*200*4      =    51,200
    float*  cWs    = (float*) (ws + 8964096);          // 64*64*4       =    16,384
    ushort* BhatWs = (ushort*)(ws + 8980480);          // 64*64*224*2   = 1,835,008
    ushort* UTWs   = (ushort*)(ws + 10815488);         // 64*224*64*2   = 1,835,008
                                                       // total         = 12,650,496

    dim3 blk(256, 1, 1);
    k0_prep<<<dim3(64, 1, 1), blk, 0, stream>>>(Ug, wg, bg, BhatWs, UTWs, cWs);
    k1_gemm1_softmax<<<dim3(16, 64, 1), blk, 0, stream>>>(Hg, BhatWs, cWs, qmg, Pws, SmaxWs);
    k2a_softmaxT<<<dim3(64, 1, 1), blk, 0, stream>>>(cmg, SmaxWs, aWs, HbarWs);
    k2b_hbar<<<dim3(16, 64, 1), blk, 0, stream>>>(Hg, aWs, HbarWs);
    k3_gemm2_out<<<dim3(16, 64, 1), blk, 0, stream>>>(Hg, UTWs, Pws, HbarWs, Gout);
}